// Round 7
// baseline (78.991 us; speedup 1.0000x reference)
//
#include <hip/hip_runtime.h>

// DataTermLayer: per-pixel optical-flow data-term update.
// Inputs (float32, each B*H*W = 16*1024*1024):
//   d_in[0]=I1, d_in[1]=I2, d_in[2]=u, d_in[3]=v
// Output: d_out = [u_next (N floats) | v_next (N floats)]
//
// Faithful-to-reference: grad_x := dy (vertical diff), grad_y := dx
// (horizontal diff) — the Python source swaps them.
//
// R7: latency-structure rewrite (R6 showed conflicts are NOT critical;
// all pipes <35% busy -> latency-bound).
//  - Fill via async global_load_lds (linear LDS dest = uniform+lane*4,
//    per-lane clamped global src). No VGPR round-trip, one vmcnt drain
//    at the barrier instead of per-element load->ds_write chains.
//  - u/v/I2 dwordx4 loads issued BEFORE the fill: latency hides under DMA.
//  - 128x16 tile, 8 px/thread (rows r and r+8): 2 independent chains,
//    fill redundancy 2.27 -> 1.71 reads/px, half the blocks/barriers.
//  - Gradients from LDS via ds_read_b128 (LW=140 keeps rows 16B-aligned);
//    clamped fill => edge-zero gradients and right/bottom cases automatic.

#define ALPHA 0.15f
#define IMG_H 1024
#define IMG_W 1024
#define TW 128
#define TH 16
#define HALO 4
#define LW 140          // 4 left halo + 128 + 8 right (rows 16B-aligned)
#define LH 25           // 4 top halo + 16 + 5 bottom
#define LDS_N 3584      // 14 * 256 >= LH*LW (=3500), padded for branchless fill

typedef float f32x4 __attribute__((ext_vector_type(4)));

__global__ __launch_bounds__(256) void dataterm_kernel(
        const float* __restrict__ I1,
        const float* __restrict__ I2,
        const float* __restrict__ u,
        const float* __restrict__ v,
        float* __restrict__ out_u,
        float* __restrict__ out_v) {
    const int W = IMG_W, H = IMG_H;
    const int t   = threadIdx.x;
    const int tx0 = blockIdx.x * TW;
    const int ty0 = blockIdx.y * TH;
    const int b   = blockIdx.z;

    const float* __restrict__ I1b = I1 + (size_t)b * (size_t)(H * W);

    __shared__ float S[LDS_N];

    // thread -> 4 consecutive pixels in rows r and r+8 of the tile
    const int r  = t >> 5;           // 0..7
    const int cb = (t & 31) << 2;    // 0..124
    const int h0 = ty0 + r;
    const int wb = tx0 + cb;
    const int p0 = (b * H + h0) * W + wb;
    const int p1 = p0 + 8 * W;

    // --- register loads first: HBM latency overlaps the fill DMA ---
    f32x4 u4a = *(const f32x4*)(u + p0);
    f32x4 v4a = *(const f32x4*)(v + p0);
    f32x4 i2a = *(const f32x4*)(I2 + p0);
    f32x4 u4b = *(const f32x4*)(u + p1);
    f32x4 v4b = *(const f32x4*)(v + p1);
    f32x4 i2b = *(const f32x4*)(I2 + p1);

    // --- async clamped tile fill: linear LDS dest, per-lane global src ---
    #pragma unroll
    for (int j = 0; j < 14; ++j) {
        int f  = t + 256 * j;
        int ly = f / LW;                         // 0..25 (25 = pad rows)
        int lx = f - ly * LW;
        int gy = min(max(ty0 - HALO + min(ly, LH - 1), 0), H - 1);
        int gx = min(max(tx0 - HALO + lx, 0), W - 1);
        __builtin_amdgcn_global_load_lds(
            (const __attribute__((address_space(1))) void*)(I1b + gy * W + gx),
            (__attribute__((address_space(3))) void*)(S + f), 4, 0, 0);
    }
    __syncthreads();

    float ou[8], ov[8];

    auto proc4 = [&](int h, int cl, const f32x4& u4, const f32x4& v4,
                     const f32x4& i24, float* ru, float* rv) {
        // gradients from LDS (clamped fill => zero at image edges)
        f32x4 c4 = *(const f32x4*)(S + cl);          // ds_read_b128
        f32x4 d4 = *(const f32x4*)(S + cl + LW);     // next row
        float c4r = S[cl + 4];
        float gyv[4] = { d4.x - c4.x, d4.y - c4.y, d4.z - c4.z, d4.w - c4.w };
        float gxv[4] = { c4.y - c4.x, c4.z - c4.y, c4.w - c4.z, c4r - c4.w };
        float uu[4] = { u4.x, u4.y, u4.z, u4.w };
        float vv[4] = { v4.x, v4.y, v4.z, v4.w };
        float i2[4] = { i24.x, i24.y, i24.z, i24.w };

        #pragma unroll
        for (int i = 0; i < 4; ++i) {
            float x = (float)(wb + i) + 0.5f * uu[i];
            float y = (float)h        + 0.5f * vv[i];

            float x0f = floorf(x);
            float y0f = floorf(y);
            float wx1 = x - x0f;
            float wx0 = 1.0f - wx1;
            float wy1 = y - y0f;
            float wy0 = 1.0f - wy1;

            int x0 = (int)x0f, y0 = (int)y0f;
            int x1 = x0 + 1,   y1 = y0 + 1;

            float vx0 = (x0 >= 0 && x0 <= W - 1) ? 1.0f : 0.0f;
            float vx1 = (x1 >= 0 && x1 <= W - 1) ? 1.0f : 0.0f;
            float vy0 = (y0 >= 0 && y0 <= H - 1) ? 1.0f : 0.0f;
            float vy1 = (y1 >= 0 && y1 <= H - 1) ? 1.0f : 0.0f;

            int lx0 = x0 - tx0 + HALO;
            int ly0 = y0 - ty0 + HALO;

            float g00, g01, g10, g11;
            if ((unsigned)lx0 <= (unsigned)(LW - 2) &&
                (unsigned)ly0 <= (unsigned)(LH - 2)) {
                int q = ly0 * LW + lx0;
                g00 = S[q]          * (vy0 * vx0);
                g01 = S[q + 1]      * (vy0 * vx1);
                g10 = S[q + LW]     * (vy1 * vx0);
                g11 = S[q + LW + 1] * (vy1 * vx1);
            } else {
                // out-of-halo fallback (never taken for 0.5*N(0,1) flow)
                int x0c = min(max(x0, 0), W - 1);
                int x1c = min(max(x1, 0), W - 1);
                int y0c = min(max(y0, 0), H - 1);
                int y1c = min(max(y1, 0), H - 1);
                g00 = I1b[y0c * W + x0c] * (vy0 * vx0);
                g01 = I1b[y0c * W + x1c] * (vy0 * vx1);
                g10 = I1b[y1c * W + x0c] * (vy1 * vx0);
                g11 = I1b[y1c * W + x1c] * (vy1 * vx1);
            }

            float warped = g00 * (wy0 * wx0)
                         + g01 * (wy0 * wx1)
                         + g10 * (wy1 * wx0)
                         + g11 * (wy1 * wx1);

            float dataTerm = warped - i2[i];
            ru[i] = uu[i] - ALPHA * dataTerm * gyv[i];
            rv[i] = vv[i] - ALPHA * dataTerm * gxv[i];
        }
    };

    const int clA = (HALO + r) * LW + HALO + cb;
    proc4(h0,     clA,            u4a, v4a, i2a, ou,     ov);
    proc4(h0 + 8, clA + 8 * LW,   u4b, v4b, i2b, ou + 4, ov + 4);

    f32x4 ruA = { ou[0], ou[1], ou[2], ou[3] };
    f32x4 rvA = { ov[0], ov[1], ov[2], ov[3] };
    f32x4 ruB = { ou[4], ou[5], ou[6], ou[7] };
    f32x4 rvB = { ov[4], ov[5], ov[6], ov[7] };
    __builtin_nontemporal_store(ruA, (f32x4*)(out_u + p0));
    __builtin_nontemporal_store(rvA, (f32x4*)(out_v + p0));
    __builtin_nontemporal_store(ruB, (f32x4*)(out_u + p1));
    __builtin_nontemporal_store(rvB, (f32x4*)(out_v + p1));
}

extern "C" void kernel_launch(void* const* d_in, const int* in_sizes, int n_in,
                              void* d_out, int out_size, void* d_ws, size_t ws_size,
                              hipStream_t stream) {
    const float* I1 = (const float*)d_in[0];
    const float* I2 = (const float*)d_in[1];
    const float* u  = (const float*)d_in[2];
    const float* v  = (const float*)d_in[3];

    int total = in_sizes[0];               // B*H*W = 16 * 1024 * 1024
    float* out_u = (float*)d_out;
    float* out_v = (float*)d_out + total;

    dim3 grid(IMG_W / TW, IMG_H / TH, total / (IMG_H * IMG_W));
    dataterm_kernel<<<grid, dim3(256), 0, stream>>>(I1, I2, u, v, out_u, out_v);
}

// Round 8
// 65.889 us; speedup vs baseline: 1.1989x; 1.1989x over previous
//
#include <hip/hip_runtime.h>

// DataTermLayer: per-pixel optical-flow data-term update.
// Inputs (float32, each B*H*W = 16*1024*1024):
//   d_in[0]=I1, d_in[1]=I2, d_in[2]=u, d_in[3]=v
// Output: d_out = [u_next (N floats) | v_next (N floats)]
//
// Faithful-to-reference: grad_x := dy (vertical diff), grad_y := dx
// (horizontal diff) — the Python source swaps them.
//
// R8 = R5 structure (best: 70.7us) with the LDS-pipe fix the cycle
// arithmetic demands: ~38us/CU of LDS issue+conflict cycles in R5 were
// dominated by 12 scalar gradient reads/thread at lane-stride-4 (8-way
// bank conflict). Read gradients as ds_read_b128 (contiguous 16B/lane =
// conflict-free): 12 scalar -> 2x b128 + 1 scalar. LW 137->140 for 16B
// row alignment. Gathers stay scalar & unswizzled (R6 proved their
// statistical conflicts are overlapped). u/v/I2 loads hoisted above the
// fill so their HBM latency hides under it. Branchless 10-iter fill.

#define ALPHA 0.15f
#define IMG_H 1024
#define IMG_W 1024
#define TW 128
#define TH 8
#define HALO 4
#define LW 140          // 4 left halo + 128 + 8 right; rows 16B-aligned
#define LH 17           // 4 top halo + 8 + 5 bottom
#define LDS_N 2560      // 10 * 256 >= LH*LW (=2380)

typedef float f32x4 __attribute__((ext_vector_type(4)));

__global__ __launch_bounds__(256) void dataterm_kernel(
        const float* __restrict__ I1,
        const float* __restrict__ I2,
        const float* __restrict__ u,
        const float* __restrict__ v,
        float* __restrict__ out_u,
        float* __restrict__ out_v) {
    const int W = IMG_W, H = IMG_H;
    const int t   = threadIdx.x;
    const int tx0 = blockIdx.x * TW;
    const int ty0 = blockIdx.y * TH;
    const int b   = blockIdx.z;

    const float* __restrict__ I1b = I1 + (size_t)b * (size_t)(H * W);

    __shared__ float S[LDS_N];

    // thread -> 4 consecutive pixels of one row
    const int r  = t >> 5;           // row within tile, 0..7
    const int cb = (t & 31) << 2;    // col base within tile, 0..124
    const int h  = ty0 + r;
    const int wb = tx0 + cb;
    const int p  = (b * H + h) * W + wb;

    // --- register loads first: HBM latency overlaps the fill ---
    f32x4 u4  = *(const f32x4*)(u + p);
    f32x4 v4  = *(const f32x4*)(v + p);
    f32x4 i24 = *(const f32x4*)(I2 + p);

    // --- cooperative clamped tile fill (branchless, 10 iters) ---
    #pragma unroll
    for (int j = 0; j < 10; ++j) {
        int f  = t + 256 * j;                    // 0..2559
        int ly = f / LW;                         // 0..18
        int lx = f - ly * LW;
        int gy = min(max(ty0 - HALO + min(ly, LH - 1), 0), H - 1);
        int gx = min(max(tx0 - HALO + lx, 0), W - 1);
        S[f] = I1b[gy * W + gx];
    }
    __syncthreads();

    // --- gradients from LDS via conflict-free ds_read_b128 ---
    const int cl = (HALO + r) * LW + HALO + cb;  // 16B-aligned
    f32x4 c4 = *(const f32x4*)(S + cl);
    f32x4 d4 = *(const f32x4*)(S + cl + LW);
    float c4r = S[cl + 4];

    float gyv[4] = { d4.x - c4.x, d4.y - c4.y, d4.z - c4.z, d4.w - c4.w };
    float gxv[4] = { c4.y - c4.x, c4.z - c4.y, c4.w - c4.z, c4r - c4.w };

    float uu[4] = { u4.x, u4.y, u4.z, u4.w };
    float vv[4] = { v4.x, v4.y, v4.z, v4.w };
    float i2[4] = { i24.x, i24.y, i24.z, i24.w };
    float ru[4], rv[4];

    #pragma unroll
    for (int i = 0; i < 4; ++i) {
        float x = (float)(wb + i) + 0.5f * uu[i];
        float y = (float)h        + 0.5f * vv[i];

        float x0f = floorf(x);
        float y0f = floorf(y);
        float wx1 = x - x0f;
        float wx0 = 1.0f - wx1;
        float wy1 = y - y0f;
        float wy0 = 1.0f - wy1;

        int x0 = (int)x0f, y0 = (int)y0f;
        int x1 = x0 + 1,   y1 = y0 + 1;

        float vx0 = (x0 >= 0 && x0 <= W - 1) ? 1.0f : 0.0f;
        float vx1 = (x1 >= 0 && x1 <= W - 1) ? 1.0f : 0.0f;
        float vy0 = (y0 >= 0 && y0 <= H - 1) ? 1.0f : 0.0f;
        float vy1 = (y1 >= 0 && y1 <= H - 1) ? 1.0f : 0.0f;

        int lx0 = x0 - tx0 + HALO;
        int ly0 = y0 - ty0 + HALO;

        float g00, g01, g10, g11;
        if ((unsigned)lx0 <= (unsigned)(LW - 2) &&
            (unsigned)ly0 <= (unsigned)(LH - 2)) {
            // in-tile (the always case): gather from LDS
            int q = ly0 * LW + lx0;
            g00 = S[q]          * (vy0 * vx0);
            g01 = S[q + 1]      * (vy0 * vx1);
            g10 = S[q + LW]     * (vy1 * vx0);
            g11 = S[q + LW + 1] * (vy1 * vx1);
        } else {
            // out-of-halo fallback (never taken for 0.5*N(0,1) flow)
            int x0c = min(max(x0, 0), W - 1);
            int x1c = min(max(x1, 0), W - 1);
            int y0c = min(max(y0, 0), H - 1);
            int y1c = min(max(y1, 0), H - 1);
            g00 = I1b[y0c * W + x0c] * (vy0 * vx0);
            g01 = I1b[y0c * W + x1c] * (vy0 * vx1);
            g10 = I1b[y1c * W + x0c] * (vy1 * vx0);
            g11 = I1b[y1c * W + x1c] * (vy1 * vx1);
        }

        float warped = g00 * (wy0 * wx0)
                     + g01 * (wy0 * wx1)
                     + g10 * (wy1 * wx0)
                     + g11 * (wy1 * wx1);

        float dataTerm = warped - i2[i];
        ru[i] = uu[i] - ALPHA * dataTerm * gyv[i];
        rv[i] = vv[i] - ALPHA * dataTerm * gxv[i];
    }

    f32x4 ruv = { ru[0], ru[1], ru[2], ru[3] };
    f32x4 rvv = { rv[0], rv[1], rv[2], rv[3] };
    __builtin_nontemporal_store(ruv, (f32x4*)(out_u + p));
    __builtin_nontemporal_store(rvv, (f32x4*)(out_v + p));
}

extern "C" void kernel_launch(void* const* d_in, const int* in_sizes, int n_in,
                              void* d_out, int out_size, void* d_ws, size_t ws_size,
                              hipStream_t stream) {
    const float* I1 = (const float*)d_in[0];
    const float* I2 = (const float*)d_in[1];
    const float* u  = (const float*)d_in[2];
    const float* v  = (const float*)d_in[3];

    int total = in_sizes[0];               // B*H*W = 16 * 1024 * 1024
    float* out_u = (float*)d_out;
    float* out_v = (float*)d_out + total;

    dim3 grid(IMG_W / TW, IMG_H / TH, total / (IMG_H * IMG_W));
    dataterm_kernel<<<grid, dim3(256), 0, stream>>>(I1, I2, u, v, out_u, out_v);
}